// Round 6
// baseline (485.596 us; speedup 1.0000x reference)
//
#include <hip/hip_runtime.h>
#include <math.h>

// Problem constants
#define NB 64
#define NN 4096
#define ND 128
#define NS 8
#define NH 256
#define CHUNKS 8             // attn blocks per batch
#define ROWS_PER_CHUNK 512   // NN / CHUNKS

static constexpr float EPSA  = 1e-8f;
static constexpr float LNE   = 1e-5f;
static constexpr float SCALE = 0.08838834764831845f;  // 1/sqrt(128)
static constexpr float LOG2E = 1.4426950408889634f;

// ---- workspace layout (float offsets) ----
#define OFF_SLOTS 0                        // [64][8][128]
#define OFF_QK    65536                    // [64][8][128]  raw qk (scale folded)
#define OFF_WC    131072                   // [384][128]  W_ih @ Wv
#define OFF_M2T   180224                   // [128][128]
#define OFF_QKB   196608                   // [128]
#define OFF_PA1   196736                   // [64][8][8][128] partial acc1 (raw space)
#define OFF_PA2   721024                   // [64][8][8]      partial acc2
#define OFF_PA3   725120                   // [64][8][8]      partial acc3 (colsums)

__device__ __forceinline__ float dot4f(float4 a, float4 b) {
    return fmaf(a.x, b.x, fmaf(a.y, b.y, fmaf(a.z, b.z, a.w * b.w)));
}

// DPP-based lane-group reductions (VALU pipe, no LDS).
template <int CTRL>
__device__ __forceinline__ float dpp_radd(float v) {
    return v + __int_as_float(__builtin_amdgcn_update_dpp(
        __float_as_int(v), __float_as_int(v), CTRL, 0xF, 0xF, false));
}
__device__ __forceinline__ float red16(float v) {   // sum over each 16-lane row; result in all lanes
    v = dpp_radd<0xB1>(v); v = dpp_radd<0x4E>(v);
    v = dpp_radd<0x141>(v); v = dpp_radd<0x140>(v);
    return v;
}
__device__ __forceinline__ float red8(float v) {    // sum over each 8-lane group; result in all lanes
    v = dpp_radd<0xB1>(v); v = dpp_radd<0x4E>(v); v = dpp_radd<0x141>(v);
    return v;
}

// ---------------------------------------------------------------------------
// K0: weight folding + slot init.
// ---------------------------------------------------------------------------
__global__ __launch_bounds__(256) void prep_kernel(
    const float* __restrict__ noise, const float* __restrict__ ln_s_w,
    const float* __restrict__ ln_s_b, const float* __restrict__ slot_mu,
    const float* __restrict__ slot_sigma, const float* __restrict__ Wq,
    const float* __restrict__ Wk, const float* __restrict__ Wv,
    const float* __restrict__ W_ih, float* __restrict__ ws)
{
    int bid = blockIdx.x, t = threadIdx.x;
    if (bid < 32) {
        int i0 = (bid * 256 + t) * 8;
        int d0 = i0 & 127;
        float o[8];
#pragma unroll
        for (int j = 0; j < 8; j++) {
            float sg = slot_sigma[d0 + j];
            float sp = fmaxf(sg, 0.f) + log1pf(expf(-fabsf(sg)));  // softplus
            o[j] = fmaf(sp, noise[i0 + j], slot_mu[d0 + j]);
        }
        float4* dst = (float4*)(ws + OFF_SLOTS + i0);
        dst[0] = make_float4(o[0], o[1], o[2], o[3]);
        dst[1] = make_float4(o[4], o[5], o[6], o[7]);
    } else if (bid < 224) {
        int g = (bid - 32) * 2 + (t >> 7);
        int f = t & 127;
        const float* wih = W_ih + g * ND;
        float acc = 0.f;
        for (int e = 0; e < ND; e++) acc = fmaf(wih[e], Wv[e * ND + f], acc);
        ws[OFF_WC + g * ND + f] = acc;
    } else {
        int dp = (bid - 224) * 2 + (t >> 7);
        int d = t & 127;
        float acc = 0.f;
        for (int e = 0; e < ND; e++) acc = fmaf(Wq[e * ND + d], Wk[e * ND + dp], acc);
        ws[OFF_M2T + dp * ND + d] = SCALE * ln_s_w[d] * acc;
        float c = ln_s_b[d] * acc;
#pragma unroll
        for (int m = 1; m <= 32; m <<= 1) c += __shfl_xor(c, m, 64);
        __shared__ float red[4];
        if ((t & 63) == 0) red[t >> 6] = c;
        __syncthreads();
        if (t == 0)   ws[OFF_QKB + dp] = SCALE * (red[0] + red[1]);
        if (t == 128) ws[OFF_QKB + dp] = SCALE * (red[2] + red[3]);
    }
}

// ---------------------------------------------------------------------------
// qk for iteration 0.  grid 64 (per batch), 512 threads.  Writes RAW qk.
// ---------------------------------------------------------------------------
__global__ __launch_bounds__(512) void qk0_kernel(float* __restrict__ ws)
{
    __shared__ float sh_s[NS * ND];
    __shared__ float sh_ln[NS * ND];
    int b = blockIdx.x, t = threadIdx.x;
    sh_s[t]       = ws[OFF_SLOTS + b * NS * ND + t];
    sh_s[t + 512] = ws[OFF_SLOTS + b * NS * ND + t + 512];
    __syncthreads();
    {   // LN(raw): wave w handles slot w, 64 lanes x 2 cols
        int wid = t >> 6, l = t & 63;
        float v0 = sh_s[wid * ND + 2 * l], v1 = sh_s[wid * ND + 2 * l + 1];
        float s1 = v0 + v1, s2 = fmaf(v0, v0, v1 * v1);
#pragma unroll
        for (int m = 1; m <= 32; m <<= 1) { s1 += __shfl_xor(s1, m, 64); s2 += __shfl_xor(s2, m, 64); }
        float mean = s1 * (1.f / 128.f);
        float var = fmaf(-mean, mean, s2 * (1.f / 128.f));
        float tv = var + LNE;
        float rs = rsqrtf(tv); rs = rs * (1.5f - 0.5f * tv * rs * rs);
        sh_ln[wid * ND + 2 * l]     = (v0 - mean) * rs;
        sh_ln[wid * ND + 2 * l + 1] = (v1 - mean) * rs;
    }
    __syncthreads();
    {   // qk[s][dp] = qkb[dp] + ln[s] . M2T[dp]   (8 lanes per output)
        int g = t >> 3, c = t & 7, s = g >> 3, dp0 = g & 7;
        const float4* lp = (const float4*)(sh_ln + s * ND + c * 16);
        float4 l0 = lp[0], l1 = lp[1], l2 = lp[2], l3 = lp[3];
#pragma unroll 2
        for (int j = 0; j < 16; j++) {
            int dp = dp0 + 8 * j;
            const float4* m4 = (const float4*)(ws + OFF_M2T + dp * ND + c * 16);
            float a = dot4f(m4[0], l0) + dot4f(m4[1], l1) + dot4f(m4[2], l2) + dot4f(m4[3], l3);
            a = red8(a);
            if (c == 0) ws[OFF_QK + b * NS * ND + s * ND + dp] = a + ws[OFF_QKB + dp];
        }
    }
}

// ---------------------------------------------------------------------------
// Main fused pass, restructured: qk2 (log2e*w*qk) held in REGISTERS; LN
// folded into dot algebra (only stats computed per row); accumulation in
// raw-x space.  Zero LDS traffic in the hot loop.
//   dots*log2e = rs*(x.qk2_s) - rs*m*S1_s + B2_s ;  p = softmax (base 2)
//   acc1[s][e] += (p*rs)*x_e ; acc2[s] += p*rs*m ; acc3[s] += p
// ---------------------------------------------------------------------------
__global__ __launch_bounds__(256) void attn_kernel(
    const float* __restrict__ inp, const float* __restrict__ lnw,
    const float* __restrict__ lnb, float* __restrict__ ws)
{
    __shared__ float red_lds[4][NS][ND];
    __shared__ float cs2_lds[4][NS];
    __shared__ float cs3_lds[4][NS];
    int t = threadIdx.x;
    int b = blockIdx.x >> 3, chunk = blockIdx.x & 7;
    int w = t >> 6, lane = t & 63;
    int rg = lane >> 4, colg = lane & 15;

    // ---- prologue: fold qk into registers (once per block) ----
    float qk2[NS][8];
    float S1[NS], B2[NS];
    {
        float wv[8], bv[8];
        const float4* w4 = (const float4*)(lnw + colg * 8);
        const float4* b4 = (const float4*)(lnb + colg * 8);
        float4 wa = w4[0], wb = w4[1], ba = b4[0], bb = b4[1];
        wv[0]=wa.x; wv[1]=wa.y; wv[2]=wa.z; wv[3]=wa.w; wv[4]=wb.x; wv[5]=wb.y; wv[6]=wb.z; wv[7]=wb.w;
        bv[0]=ba.x; bv[1]=ba.y; bv[2]=ba.z; bv[3]=ba.w; bv[4]=bb.x; bv[5]=bb.y; bv[6]=bb.z; bv[7]=bb.w;
        const float* qkp = ws + OFF_QK + b * NS * ND;
#pragma unroll
        for (int si = 0; si < NS; si++) {
            const float4* qr = (const float4*)(qkp + si * ND + colg * 8);
            float4 q0 = qr[0], q1 = qr[1];
            float q8[8] = {q0.x, q0.y, q0.z, q0.w, q1.x, q1.y, q1.z, q1.w};
            float ss = 0.f, bb2 = 0.f;
#pragma unroll
            for (int j = 0; j < 8; j++) {
                float v = LOG2E * wv[j] * q8[j];
                qk2[si][j] = v;
                ss += v;
                bb2 = fmaf(bv[j], q8[j], bb2);
            }
            S1[si] = red16(ss);
            B2[si] = LOG2E * red16(bb2);
        }
    }
    float acc1[NS][8], acc2[NS], acc3[NS];
#pragma unroll
    for (int si = 0; si < NS; si++) {
        acc2[si] = 0.f; acc3[si] = 0.f;
#pragma unroll
        for (int j = 0; j < 8; j++) acc1[si][j] = 0.f;
    }

    const float* base = inp + ((size_t)b * NN + chunk * ROWS_PER_CHUNK + w * 128 + rg) * ND + colg * 8;
    for (int q = 0; q < 32; q++) {
        const float* rp = base + q * 4 * ND;
        float4 a0 = *(const float4*)rp;
        float4 a1 = *(const float4*)(rp + 4);
        float x[8] = {a0.x, a0.y, a0.z, a0.w, a1.x, a1.y, a1.z, a1.w};
        // LN stats only
        float s1 = 0.f, s2 = 0.f;
#pragma unroll
        for (int j = 0; j < 8; j++) { s1 += x[j]; s2 = fmaf(x[j], x[j], s2); }
        s1 = red16(s1); s2 = red16(s2);
        float mean = s1 * (1.f / 128.f);
        float var = fmaf(-mean, mean, s2 * (1.f / 128.f));
        float tv = var + LNE;
        float rs = rsqrtf(tv); rs = rs * (1.5f - 0.5f * tv * rs * rs);
        // dots on raw x
        float pd[NS];
#pragma unroll
        for (int si = 0; si < NS; si++) {
            float p = x[0] * qk2[si][0];
#pragma unroll
            for (int j = 1; j < 8; j++) p = fmaf(x[j], qk2[si][j], p);
            pd[si] = red16(p);
        }
        float rm = rs * mean;
#pragma unroll
        for (int si = 0; si < NS; si++)
            pd[si] = fmaf(rs, pd[si], fmaf(-rm, S1[si], B2[si]));
        float mx = fmaxf(fmaxf(fmaxf(pd[0], pd[1]), fmaxf(pd[2], pd[3])),
                         fmaxf(fmaxf(pd[4], pd[5]), fmaxf(pd[6], pd[7])));
        float ev[NS]; float es = 0.f;
#pragma unroll
        for (int si = 0; si < NS; si++) { ev[si] = exp2f(pd[si] - mx); es += ev[si]; }
        float r0 = __builtin_amdgcn_rcpf(es);
        float inv = r0 * (2.0f - es * r0);   // 1 NR step
        float invrs = inv * rs;
#pragma unroll
        for (int si = 0; si < NS; si++) {
            float pr = ev[si] * invrs;   // p * rs
            float pn = ev[si] * inv;     // p
            acc3[si] += pn;
            acc2[si] = fmaf(pr, mean, acc2[si]);
#pragma unroll
            for (int j = 0; j < 8; j++) acc1[si][j] = fmaf(pr, x[j], acc1[si][j]);
        }
    }
    // reduce across the 4 row-groups within the wave
#pragma unroll
    for (int m = 16; m <= 32; m <<= 1) {
#pragma unroll
        for (int si = 0; si < NS; si++) {
            acc2[si] += __shfl_xor(acc2[si], m, 64);
            acc3[si] += __shfl_xor(acc3[si], m, 64);
#pragma unroll
            for (int j = 0; j < 8; j++) acc1[si][j] += __shfl_xor(acc1[si][j], m, 64);
        }
    }
    if (lane < 16) {
#pragma unroll
        for (int si = 0; si < NS; si++) {
            *(float4*)&red_lds[w][si][lane * 8]     = make_float4(acc1[si][0], acc1[si][1], acc1[si][2], acc1[si][3]);
            *(float4*)&red_lds[w][si][lane * 8 + 4] = make_float4(acc1[si][4], acc1[si][5], acc1[si][6], acc1[si][7]);
        }
    }
    if (lane == 0) {
#pragma unroll
        for (int si = 0; si < NS; si++) { cs2_lds[w][si] = acc2[si]; cs3_lds[w][si] = acc3[si]; }
    }
    __syncthreads();
    float* p1 = ws + OFF_PA1 + (size_t)(b * CHUNKS + chunk) * (NS * ND);
#pragma unroll
    for (int k = 0; k < 4; k++) {
        int o = t + k * 256;
        p1[o] = red_lds[0][0][o] + red_lds[1][0][o] + red_lds[2][0][o] + red_lds[3][0][o];
    }
    if (t < NS) {
        ws[OFF_PA2 + (b * CHUNKS + chunk) * NS + t] =
            cs2_lds[0][t] + cs2_lds[1][t] + cs2_lds[2][t] + cs2_lds[3][t];
        ws[OFF_PA3 + (b * CHUNKS + chunk) * NS + t] =
            cs3_lds[0][t] + cs3_lds[1][t] + cs3_lds[2][t] + cs3_lds[3][t];
    }
}

// ---------------------------------------------------------------------------
// GRU + next-qk / final-MLP.  Folds the partial reduction + LN-space
// reconstruction.  2 blocks per batch (4 slots each), 512 thr.
// ---------------------------------------------------------------------------
template <int LAST>
__global__ __launch_bounds__(512) void gru_kernel(
    const float* __restrict__ lnw, const float* __restrict__ lnb,
    const float* __restrict__ W_hh, const float* __restrict__ b_ih,
    const float* __restrict__ b_hh, const float* __restrict__ W1,
    const float* __restrict__ b1, const float* __restrict__ W2,
    const float* __restrict__ b2, const float* __restrict__ ln_m_w,
    const float* __restrict__ ln_m_b, float* __restrict__ ws,
    float* __restrict__ out)
{
    __shared__ float sh_nr[4 * ND];    // normalized updates -> new slots
    __shared__ float sh_sp[4 * ND];    // slots_prev (this half)
    __shared__ float sh_tmp[512];
    __shared__ float sh_sx[ND];        // A1s[e] = sum_s acc1[s][e]
    __shared__ float sh_a2[NS];
    __shared__ float sh_a3[NS];
    __shared__ float sh_gi[4 * 384];   // reused as h[4][256] in LAST path
    __shared__ float sh_gh[4 * 384];
    __shared__ float sh_ln[4 * ND];
    int b = blockIdx.x >> 1, sh2 = blockIdx.x & 1;
    int t = threadIdx.x;
    int e = t & 127;

    const float* pa1 = ws + OFF_PA1 + (size_t)b * CHUNKS * NS * ND;
    float r1 = 0.f;
#pragma unroll
    for (int p = 0; p < CHUNKS; p++) r1 += pa1[p * (NS * ND) + sh2 * 512 + t];
    {
        int sg = t >> 7;
        float ax = 0.f;
#pragma unroll
        for (int p = 0; p < CHUNKS; p++)
            ax += pa1[p * (NS * ND) + sg * ND + e] + pa1[p * (NS * ND) + (sg + 4) * ND + e];
        sh_tmp[t] = ax;
    }
    if (t < NS) {
        float a = 0.f;
#pragma unroll
        for (int p = 0; p < CHUNKS; p++) a += ws[OFF_PA2 + (b * CHUNKS + p) * NS + t];
        sh_a2[t] = a;
    }
    if (t >= 64 && t < 64 + NS) {
        float a = 0.f;
#pragma unroll
        for (int p = 0; p < CHUNKS; p++) a += ws[OFF_PA3 + (b * CHUNKS + p) * NS + (t - 64)];
        sh_a3[t - 64] = a;
    }
    sh_sp[t] = ws[OFF_SLOTS + b * NS * ND + sh2 * 512 + t];
    __syncthreads();
    if (t < ND) sh_sx[t] = sh_tmp[t] + sh_tmp[t + 128] + sh_tmp[t + 256] + sh_tmp[t + 384];
    __syncthreads();
    // ---- B: reconstruct LN-space updates + EPS-normalize ----
    {
        int sl_ = t >> 7;
        int s = sh2 * 4 + sl_;
        float we = lnw[e], be = lnb[e];
        float a2s = sh_a2[s], a3s = sh_a3[s];
        float A2sum = 0.f, A3sum = 0.f;
#pragma unroll
        for (int k = 0; k < NS; k++) { A2sum += sh_a2[k]; A3sum += sh_a3[k]; }
        float Sx = fmaf(we, sh_sx[e] - A2sum, be * A3sum);       // sum_n xln[n,e]
        float raw = fmaf(we, r1 - a2s, be * a3s);                // sum_n p*xln
        sh_nr[t] = (raw + EPSA * Sx) / (a3s + (float)NN * EPSA);
    }
    __syncthreads();
    // ---- C: gi = nr@WC^T + b_ih, gh = sp@W_hh^T + b_hh (8 lanes per output)
    int g = t >> 3, c = t & 7;
    int sl = g >> 4, g3 = g & 15;      // local slot 0..3, row phase 0..15
    {
        const float4* np = (const float4*)(sh_nr + sl * ND + c * 16);
        const float4* pp = (const float4*)(sh_sp + sl * ND + c * 16);
        float4 n0 = np[0], n1 = np[1], n2 = np[2], n3 = np[3];
        float4 p0 = pp[0], p1 = pp[1], p2 = pp[2], p3 = pp[3];
#pragma unroll 4
        for (int j = 0; j < 24; j++) {
            int e3 = g3 + 16 * j;
            const float4* wc4 = (const float4*)(ws + OFF_WC + e3 * ND + c * 16);
            const float4* wh4 = (const float4*)(W_hh + e3 * ND + c * 16);
            float ai = dot4f(wc4[0], n0) + dot4f(wc4[1], n1) + dot4f(wc4[2], n2) + dot4f(wc4[3], n3);
            float ah = dot4f(wh4[0], p0) + dot4f(wh4[1], p1) + dot4f(wh4[2], p2) + dot4f(wh4[3], p3);
            ai = red8(ai); ah = red8(ah);
            if (c == 0) {
                sh_gi[sl * 384 + e3] = ai + b_ih[e3];
                sh_gh[sl * 384 + e3] = ah + b_hh[e3];
            }
        }
    }
    __syncthreads();
    // ---- D: gates -> new slots
    {
        int si = t >> 7, d = t & 127;
        float gir = sh_gi[si * 384 + d],       ghr = sh_gh[si * 384 + d];
        float giz = sh_gi[si * 384 + 128 + d], ghz = sh_gh[si * 384 + 128 + d];
        float gin = sh_gi[si * 384 + 256 + d], ghn = sh_gh[si * 384 + 256 + d];
        float rr = 1.f / (1.f + expf(-(gir + ghr)));
        float z  = 1.f / (1.f + expf(-(giz + ghz)));
        float nn_ = tanhf(fmaf(rr, ghn, gin));
        float ns = fmaf(z, sh_sp[t] - nn_, nn_);
        sh_nr[t] = ns;
        if (!LAST) ws[OFF_SLOTS + b * NS * ND + sh2 * 512 + t] = ns;
    }
    __syncthreads();
    // ---- E: LN of new slots (waves 0..3, one slot each)
    {
        int wid = t >> 6, l = t & 63;
        if (wid < 4) {
            float v0 = sh_nr[wid * ND + 2 * l], v1 = sh_nr[wid * ND + 2 * l + 1];
            float s1 = v0 + v1, s2 = fmaf(v0, v0, v1 * v1);
#pragma unroll
            for (int m = 1; m <= 32; m <<= 1) { s1 += __shfl_xor(s1, m, 64); s2 += __shfl_xor(s2, m, 64); }
            float mean = s1 * (1.f / 128.f);
            float var = fmaf(-mean, mean, s2 * (1.f / 128.f));
            float tv = var + LNE;
            float rs = rsqrtf(tv); rs = rs * (1.5f - 0.5f * tv * rs * rs);
            float x0 = (v0 - mean) * rs, x1 = (v1 - mean) * rs;
            if (LAST) {
                x0 = fmaf(x0, ln_m_w[2 * l],     ln_m_b[2 * l]);
                x1 = fmaf(x1, ln_m_w[2 * l + 1], ln_m_b[2 * l + 1]);
            }
            sh_ln[wid * ND + 2 * l]     = x0;
            sh_ln[wid * ND + 2 * l + 1] = x1;
        }
    }
    __syncthreads();
    if (!LAST) {   // ---- F: raw qk for next iteration
        const float4* lp = (const float4*)(sh_ln + sl * ND + c * 16);
        float4 l0 = lp[0], l1 = lp[1], l2 = lp[2], l3 = lp[3];
#pragma unroll 2
        for (int j = 0; j < 8; j++) {
            int dp = g3 + 16 * j;
            const float4* m4 = (const float4*)(ws + OFF_M2T + dp * ND + c * 16);
            float a = dot4f(m4[0], l0) + dot4f(m4[1], l1) + dot4f(m4[2], l2) + dot4f(m4[3], l3);
            a = red8(a);
            if (c == 0) ws[OFF_QK + b * NS * ND + (sh2 * 4 + sl) * ND + dp] = a + ws[OFF_QKB + dp];
        }
    } else {       // ---- F: MLP
        const float4* lp = (const float4*)(sh_ln + sl * ND + c * 16);
        float4 l0 = lp[0], l1 = lp[1], l2 = lp[2], l3 = lp[3];
#pragma unroll 2
        for (int j = 0; j < 16; j++) {
            int hh = g3 + 16 * j;
            const float4* w14 = (const float4*)(W1 + hh * ND + c * 16);
            float a = dot4f(w14[0], l0) + dot4f(w14[1], l1) + dot4f(w14[2], l2) + dot4f(w14[3], l3);
            a = red8(a);
            if (c == 0) sh_gi[sl * NH + hh] = fmaxf(a + b1[hh], 0.f);
        }
        __syncthreads();
        const float4* hp = (const float4*)(sh_gi + sl * NH + c * 32);
        float4 h0 = hp[0], h1 = hp[1], h2 = hp[2], h3 = hp[3];
        float4 h4 = hp[4], h5 = hp[5], h6 = hp[6], h7 = hp[7];
#pragma unroll 2
        for (int j = 0; j < 8; j++) {
            int d = g3 + 16 * j;
            const float4* w24 = (const float4*)(W2 + d * NH + c * 32);
            float a = dot4f(w24[0], h0) + dot4f(w24[1], h1) + dot4f(w24[2], h2) + dot4f(w24[3], h3)
                    + dot4f(w24[4], h4) + dot4f(w24[5], h5) + dot4f(w24[6], h6) + dot4f(w24[7], h7);
            a = red8(a);
            if (c == 0) out[(size_t)b * NS * ND + (sh2 * 4 + sl) * ND + d] = a + b2[d] + sh_nr[sl * ND + d];
        }
    }
}

// ---------------------------------------------------------------------------
extern "C" void kernel_launch(void* const* d_in, const int* in_sizes, int n_in,
                              void* d_out, int out_size, void* d_ws, size_t ws_size,
                              hipStream_t stream) {
    (void)in_sizes; (void)n_in; (void)out_size; (void)ws_size;
    const float* inputs     = (const float*)d_in[0];
    const float* noise      = (const float*)d_in[1];
    const float* ln_in_w    = (const float*)d_in[2];
    const float* ln_in_b    = (const float*)d_in[3];
    const float* ln_s_w     = (const float*)d_in[4];
    const float* ln_s_b     = (const float*)d_in[5];
    const float* ln_m_w     = (const float*)d_in[6];
    const float* ln_m_b     = (const float*)d_in[7];
    const float* slot_mu    = (const float*)d_in[8];
    const float* slot_sigma = (const float*)d_in[9];
    const float* Wq         = (const float*)d_in[10];
    const float* Wk         = (const float*)d_in[11];
    const float* Wv         = (const float*)d_in[12];
    const float* W_ih       = (const float*)d_in[13];
    const float* W_hh       = (const float*)d_in[14];
    const float* b_ih       = (const float*)d_in[15];
    const float* b_hh       = (const float*)d_in[16];
    const float* W1         = (const float*)d_in[17];
    const float* b1         = (const float*)d_in[18];
    const float* W2         = (const float*)d_in[19];
    const float* b2         = (const float*)d_in[20];
    float* ws  = (float*)d_ws;
    float* out = (float*)d_out;

    hipLaunchKernelGGL(prep_kernel, dim3(288), dim3(256), 0, stream,
                       noise, ln_s_w, ln_s_b, slot_mu, slot_sigma, Wq, Wk, Wv, W_ih, ws);
    hipLaunchKernelGGL(qk0_kernel, dim3(NB), dim3(512), 0, stream, ws);
    for (int it = 0; it < 3; ++it) {
        hipLaunchKernelGGL(attn_kernel, dim3(NB * CHUNKS), dim3(256), 0, stream,
                           inputs, ln_in_w, ln_in_b, ws);
        if (it < 2) {
            hipLaunchKernelGGL((gru_kernel<0>), dim3(NB * 2), dim3(512), 0, stream,
                               ln_in_w, ln_in_b, W_hh, b_ih, b_hh, W1, b1, W2, b2,
                               ln_m_w, ln_m_b, ws, out);
        } else {
            hipLaunchKernelGGL((gru_kernel<1>), dim3(NB * 2), dim3(512), 0, stream,
                               ln_in_w, ln_in_b, W_hh, b_ih, b_hh, W1, b1, W2, b2,
                               ln_m_w, ln_m_b, ws, out);
        }
    }
}